// Round 11
// baseline (242.373 us; speedup 1.0000x reference)
//
#include <hip/hip_runtime.h>
#include <hip/hip_bf16.h>
#include <stdint.h>

typedef float v4f __attribute__((ext_vector_type(4)));
typedef short v8s __attribute__((ext_vector_type(8)));
typedef union { v8s v; unsigned u[4]; } v8u;

#define NB 40
#define XSTR 42     // xT row stride in shorts (21 dwords) — 4-way max bank aliasing

__device__ __forceinline__ unsigned short f2b(float f) {
  __hip_bfloat16 h = __float2bfloat16(f);
  unsigned short u;
  __builtin_memcpy(&u, &h, 2);
  return u;
}
__device__ __forceinline__ unsigned pk2(float lo, float hi) {
  __hip_bfloat162 h = __float22bfloat162_rn(make_float2(lo, hi));
  unsigned u;
  __builtin_memcpy(&u, &h, 4);
  return u;
}
__device__ __forceinline__ float b2f16(unsigned short h) {
  return __uint_as_float(((unsigned)h) << 16);
}
__device__ __forceinline__ float blo(unsigned u) { return __uint_as_float(u << 16); }
__device__ __forceinline__ float bhi(unsigned u) { return __uint_as_float(u & 0xFFFF0000u); }

// ws layout (bytes):
//  A1pk   @ 0        : 12288     (2t x 3nt x 2ks A^T A-frags, zero n>=40 / m>=40)
//  W2pk   @ 12288    : 32768     (2t x 4ks x 4dt B-frags of gnn_w)
//  Gpk    @ 45056    : 245760    (80kt x 3jt A-frags of gate_w^T, K n-major fl=n*64+d)
//  s1     @ 290816   : 20480     s for f<64, [t][n][d] f32
//  sNT    @ 311296   : 20480+128 s for f>=64, [t][d][n] f32 (+pad)
//  bias2T @ 331904   : 20480     gnn_b + all-BN-offset fold, [t][d][n] f32

// prep: params only. block 0: adjacency -> LN -> softmax -> A1pk (wave-parallel).
// blocks 1..63: everything else.
__global__ __launch_bounds__(256) void prep(
    const float* __restrict__ masker,
    const float* __restrict__ ln_gamma, const float* __restrict__ ln_beta,
    const float* __restrict__ gnn_w, const float* __restrict__ gnn_b,
    const float* __restrict__ bn_gamma, const float* __restrict__ bn_beta,
    const float* __restrict__ bn_mean, const float* __restrict__ bn_var,
    const float* __restrict__ gate_w,
    unsigned short* __restrict__ A1pk, unsigned short* __restrict__ W2pk,
    unsigned short* __restrict__ Gpk, float* __restrict__ s1,
    float* __restrict__ sNT, float* __restrict__ bias2T)
{
  const int tid = threadIdx.x;
  if (blockIdx.x == 0) {
    __shared__ float AtL[2 * NB * NB];
    const int w = tid >> 6, lane = tid & 63;
    #pragma unroll 1
    for (int it = 0; it < 20; ++it) {
      const int c = it * 4 + w;        // 0..79
      const int t = c / NB, n = c % NB;
      const int m = lane;              // valid < 40
      float adj = 0.f;
      if (m < NB) {
        float p = masker[((t*3+0)*NB+m)*NB+n]
                * masker[((t*3+1)*NB+m)*NB+n]
                * masker[((t*3+2)*NB+m)*NB+n];
        adj = p > 0.f ? p : 0.f;
      }
      float s = adj;
      #pragma unroll
      for (int d = 1; d < 64; d <<= 1) s += __shfl_xor(s, d);
      const float mu = s * (1.f/NB);
      const float dv = (m < NB) ? adj - mu : 0.f;
      float v2 = dv * dv;
      #pragma unroll
      for (int d = 1; d < 64; d <<= 1) v2 += __shfl_xor(v2, d);
      const float inv = rsqrtf(v2 * (1.f/NB) + 1e-5f);
      float val = -3.0e38f;
      if (m < NB) {
        float lnv = dv * inv * ln_gamma[m] + ln_beta[m];
        val = lnv + (adj != 0.f ? 0.f : -1e9f) + (m == n ? 1.f : 0.f);
      }
      float mx = val;
      #pragma unroll
      for (int d = 1; d < 64; d <<= 1) mx = fmaxf(mx, __shfl_xor(mx, d));
      const float e = (m < NB) ? __expf(val - mx) : 0.f;
      float es = e;
      #pragma unroll
      for (int d = 1; d < 64; d <<= 1) es += __shfl_xor(es, d);
      if (m < NB)
        AtL[(t*NB+n)*NB + m] = (adj != 0.f) ? e / es : 0.f;
    }
    __syncthreads();
    for (int e = tid; e < 6144; e += 256) {
      int frag = e >> 9, rem = e & 511, lane2 = rem >> 3, jj = rem & 7;
      int t = frag / 6, r2 = frag % 6, nt = r2 >> 1, ks = r2 & 1;
      int n = nt*16 + (lane2 & 15);
      int m = ks*32 + (lane2 >> 4)*8 + jj;
      A1pk[e] = f2b((n < NB && m < NB) ? AtL[(t*NB+n)*NB+m] : 0.f);
    }
  } else {
    const int gid = (blockIdx.x - 1) * 256 + tid, gsz = 63 * 256;
    for (int e = gid; e < 16384; e += gsz) {
      int frag = e >> 9, rem = e & 511, lane = rem >> 3, jj = rem & 7;
      int t = frag >> 4, ks = (frag >> 2) & 3, dt = frag & 3;
      int f = ks*32 + (lane >> 4)*8 + jj, d = dt*16 + (lane & 15);
      W2pk[e] = f2b(gnn_w[t*8192 + f*64 + d]);
    }
    // Gpk: K n-major (fl = n*64+d flat index), matches hL layout in kernelM
    for (int e = gid; e < 122880; e += gsz) {
      int frag = e >> 9, rem = e & 511, lane = rem >> 3, jj = rem & 7;
      int kt = frag / 3, jt = frag % 3;
      int fl = kt*32 + (lane >> 4)*8 + jj, j = jt*16 + (lane & 15);
      Gpk[e] = f2b(j < NB ? gate_w[fl*NB + j] : 0.f);
    }
    for (int e = gid; e < 5120; e += gsz) {
      int t = e / 2560, n = (e % 2560) / 64, d = e & 63;
      int F = (t*NB + n)*128 + d;
      s1[e] = bn_gamma[F] * rsqrtf(bn_var[F] + 1e-5f);
    }
    for (int e = gid; e < 5120; e += gsz) {
      int t = e / 2560, d = (e % 2560) / 40, n = e % 40;
      int F = (t*NB + n)*128 + 64 + d;
      sNT[e] = bn_gamma[F] * rsqrtf(bn_var[F] + 1e-5f);
    }
    for (int e4 = gid; e4 < 20480; e4 += gsz) {
      int e = e4 >> 2, part = e4 & 3;
      int t = e / 2560, d = (e % 2560) / 40, n = e % 40;
      float acc = (part == 0) ? gnn_b[(t*NB + n)*64 + d] : 0.f;
      int Fb = (t*NB + n)*128;
      int f0 = part * 32;
      for (int f = f0; f < f0 + 32; ++f) {
        float s = bn_gamma[Fb+f] * rsqrtf(bn_var[Fb+f] + 1e-5f);
        float o = bn_beta[Fb+f] - bn_mean[Fb+f] * s;
        acc += o * gnn_w[t*8192 + f*64 + d];
      }
      acc += __shfl_xor(acc, 1);
      acc += __shfl_xor(acc, 2);
      if (part == 0) bias2T[e] = acc;
    }
  }
}

// kernelM: 8 batches/block, 512 threads, t-split. Same per-wave phase costs as
// the 4-batch version, but GEMM3's 16 B-cols now hold 8 DISTINCT batches (2
// replicas instead of 4) -> GEMM3 MFMA and Gpk L2 traffic both halve.
// hL un-aliased (no pkr staging pass, one less barrier). LDS ~140 KB,
// 1 block/CU. XCD t-pair swizzle: blocks (bid, bid+8) share b0 -> same XCD
// -> t=1 block's x reads hit L2.
__global__ __launch_bounds__(512) void kernelM(
    const float* __restrict__ x,
    const unsigned short* __restrict__ A1pk, const unsigned short* __restrict__ W2pk,
    const unsigned short* __restrict__ Gpk, const float* __restrict__ s1,
    const float* __restrict__ sNT, const float* __restrict__ bias2T,
    const float* __restrict__ gate_b, float* __restrict__ out)
{
  __shared__ __align__(16) unsigned short hc[320 * 136];  // 87040 B (xT stage / U|V)
  __shared__ __align__(16) unsigned short hL[8 * 2568];   // 41088 B
  __shared__ float pj[64 * 48];                           // 12288 B

  const int tid = threadIdx.x;
  const int lane = tid & 63;
  const int w = tid >> 6;              // 0..7
  const int l = lane & 15, q = lane >> 4;
  const int bid = blockIdx.x;
  const int t  = (bid >> 3) & 1;
  const int bg = (bid & 7) | ((bid >> 4) << 3);   // 0..1023, t-pair -> same XCD
  const int b0 = bg * 8;
  unsigned* hcU = (unsigned*)hc;

  const float* xblk = x + (size_t)b0 * 2560;

  // ---- load x f32 -> packed bf16 regs (coalesced) ----
  uint4 xr[5];
  #pragma unroll
  for (int it = 0; it < 5; ++it) {
    const int c = it * 512 + tid, row = c >> 3, dp8 = c & 7;
    const float* xp = xblk + row * 64 + dp8 * 8;
    const float4 f0 = *(const float4*)xp;
    const float4 f1 = *(const float4*)(xp + 4);
    xr[it] = make_uint4(pk2(f0.x, f0.y), pk2(f0.z, f0.w),
                        pk2(f1.x, f1.y), pk2(f1.z, f1.w));
  }
  // ---- zero xT pads: col-pad dword 20 of each of 512 rows + 16-dword tail ----
  for (int k = tid; k < 528; k += 512)
    hcU[(k < 512) ? (k * 21 + 20) : (10752 + (k - 512))] = 0u;
  // ---- xT stage: rows R=(bq*64+d), XSTR=42-short stride ----
  #pragma unroll
  for (int it = 0; it < 5; ++it) {
    const int c = it * 512 + tid, row = c >> 3, dp8 = c & 7;
    const int bq = row / NB, n = row - bq * NB;
    unsigned short* base = hc + (bq * 64 + dp8 * 8) * XSTR + n;
    const unsigned uu0 = xr[it].x, uu1 = xr[it].y, uu2 = xr[it].z, uu3 = xr[it].w;
    base[0*XSTR] = (unsigned short)(uu0 & 0xFFFF);
    base[1*XSTR] = (unsigned short)(uu0 >> 16);
    base[2*XSTR] = (unsigned short)(uu1 & 0xFFFF);
    base[3*XSTR] = (unsigned short)(uu1 >> 16);
    base[4*XSTR] = (unsigned short)(uu2 & 0xFFFF);
    base[5*XSTR] = (unsigned short)(uu2 >> 16);
    base[6*XSTR] = (unsigned short)(uu3 & 0xFFFF);
    base[7*XSTR] = (unsigned short)(uu3 >> 16);
  }
  __syncthreads();
  // ---- b1 frags: R 0..511 across 8 waves; 4 dword loads each; overrun slots
  // land on next row's finite data / zeroed pads and multiply A1pk zeros ----
  v8s b1[4][2];
  #pragma unroll
  for (int i = 0; i < 4; ++i) {
    const int R = (w * 4 + i) * 16 + l;   // 0..511
    #pragma unroll
    for (int ks = 0; ks < 2; ++ks) {
      const unsigned* p = hcU + R * 21 + ks * 16 + q * 4;
      v8u uu;
      uu.u[0] = p[0]; uu.u[1] = p[1]; uu.u[2] = p[2]; uu.u[3] = p[3];
      b1[i][ks] = uu.v;
    }
  }
  __syncthreads();

  // per-t fragments
  v8s a1[3][2], w2[4];
  #pragma unroll
  for (int nt = 0; nt < 3; ++nt)
    #pragma unroll
    for (int ks = 0; ks < 2; ++ks)
      a1[nt][ks] = *(const v8s*)(A1pk + (((t*3 + nt)*2 + ks) << 9) + lane*8);
  #pragma unroll
  for (int ks = 0; ks < 4; ++ks)
    w2[ks] = *(const v8s*)(W2pk + (((t*4 + ks)*4 + (w & 3)) << 9) + lane*8);

  // ---- Phase A: hc x-half = s1 .* x ----
  #pragma unroll
  for (int it = 0; it < 5; ++it) {
    const int c = it*512 + tid;
    const int row = c >> 3, dp8 = c & 7;       // row = (bb,n) 0..319
    const uint4 xv = xr[it];
    const int n = row % NB;
    const float4 sA = *(const float4*)(s1 + (t*NB + n)*64 + dp8*8);
    const float4 sB = *(const float4*)(s1 + (t*NB + n)*64 + dp8*8 + 4);
    uint4 p;
    p.x = pk2(blo(xv.x)*sA.x, bhi(xv.x)*sA.y);
    p.y = pk2(blo(xv.y)*sA.z, bhi(xv.y)*sA.w);
    p.z = pk2(blo(xv.z)*sB.x, bhi(xv.z)*sB.y);
    p.w = pk2(blo(xv.w)*sB.z, bhi(xv.w)*sB.w);
    *(uint4*)(hcU + row*68 + dp8*4) = p;
  }
  // ---- GEMM1 + scale -> hc nei-half ----
  #pragma unroll
  for (int i = 0; i < 4; ++i) {
    const int R = (w*4+i)*16 + l;              // 0..511
    const int bb = R >> 6, d = R & 63;
    #pragma unroll
    for (int nt = 0; nt < 3; ++nt) {
      v4f acc = {0.f, 0.f, 0.f, 0.f};
      acc = __builtin_amdgcn_mfma_f32_16x16x32_bf16(a1[nt][0], b1[i][0], acc, 0, 0, 0);
      acc = __builtin_amdgcn_mfma_f32_16x16x32_bf16(a1[nt][1], b1[i][1], acc, 0, 0, 0);
      const float4 sv = *(const float4*)(sNT + (t*64+d)*40 + nt*16 + q*4);
      #pragma unroll
      for (int r = 0; r < 4; ++r) {
        int n = nt*16 + q*4 + r;
        if (n < NB) hc[(bb*NB + n)*136 + 64 + d] = f2b(acc[r]*sv[r]);
      }
    }
  }
  __syncthreads();
  // ---- GEMM2 + bias2T -> hL directly (un-aliased, no staging pass) ----
  #pragma unroll
  for (int mj = 0; mj < 10; ++mj) {
    const int mt = (w >> 2) * 10 + mj;         // waves 0-3: mt 0..9; 4-7: 10..19
    v4f acc = {0.f, 0.f, 0.f, 0.f};
    #pragma unroll
    for (int ks = 0; ks < 4; ++ks) {
      v8s af = *(const v8s*)(hc + (mt*16 + l)*136 + ks*32 + q*8);
      acc = __builtin_amdgcn_mfma_f32_16x16x32_bf16(af, w2[ks], acc, 0, 0, 0);
    }
    const int d = (w & 3)*16 + l;
    const int G = mt*16 + q*4;                 // 0..316, 4-aligned, no batch-cross
    const int bb = G / NB, n0 = G - bb*NB;
    const float4 bv = *(const float4*)(bias2T + (t*64+d)*40 + n0);
    hL[bb*2568 + (n0+0)*64 + d] = f2b(acc[0] + bv.x);
    hL[bb*2568 + (n0+1)*64 + d] = f2b(acc[1] + bv.y);
    hL[bb*2568 + (n0+2)*64 + d] = f2b(acc[2] + bv.z);
    hL[bb*2568 + (n0+3)*64 + d] = f2b(acc[3] + bv.w);
  }
  __syncthreads();
  // ---- GEMM3: logits; 16 B-cols = 8 distinct batches x2; depth-2 prefetch ----
  v4f ac0 = {0,0,0,0}, ac1 = {0,0,0,0}, ac2 = {0,0,0,0};
  {
    const unsigned short* hb = hL + (l & 7)*2568 + q*8;
    v8s pg0[2], pg1[2], pg2[2], pbf[2];
    #pragma unroll
    for (int s = 0; s < 2; ++s) {
      const int kt = w + s*8;
      pg0[s] = *(const v8s*)(Gpk + ((kt*3+0) << 9) + lane*8);
      pg1[s] = *(const v8s*)(Gpk + ((kt*3+1) << 9) + lane*8);
      pg2[s] = *(const v8s*)(Gpk + ((kt*3+2) << 9) + lane*8);
      pbf[s] = *(const v8s*)(hb + kt*32);
    }
    #pragma unroll
    for (int i = 0; i < 10; ++i) {
      const int cur = i & 1;
      const v8s G0 = pg0[cur], G1 = pg1[cur], G2 = pg2[cur], BF = pbf[cur];
      if (i < 8) {
        const int ktn = w + (i+2)*8;
        pg0[cur] = *(const v8s*)(Gpk + ((ktn*3+0) << 9) + lane*8);
        pg1[cur] = *(const v8s*)(Gpk + ((ktn*3+1) << 9) + lane*8);
        pg2[cur] = *(const v8s*)(Gpk + ((ktn*3+2) << 9) + lane*8);
        pbf[cur] = *(const v8s*)(hb + ktn*32);
      }
      ac0 = __builtin_amdgcn_mfma_f32_16x16x32_bf16(G0, BF, ac0, 0, 0, 0);
      ac1 = __builtin_amdgcn_mfma_f32_16x16x32_bf16(G1, BF, ac1, 0, 0, 0);
      ac2 = __builtin_amdgcn_mfma_f32_16x16x32_bf16(G2, BF, ac2, 0, 0, 0);
    }
  }
  if (l < 8) {
    #pragma unroll
    for (int r = 0; r < 4; ++r) {
      pj[(w*8 + l)*48 +  0 + q*4 + r] = ac0[r];
      pj[(w*8 + l)*48 + 16 + q*4 + r] = ac1[r];
      pj[(w*8 + l)*48 + 32 + q*4 + r] = ac2[r];
    }
  }
  __syncthreads();
  // ---- per-wave softmax (batch = w) + pool ----
  {
    float v = -3.0e38f;
    if (lane < NB) {
      v = gate_b[lane];
      #pragma unroll
      for (int ww = 0; ww < 8; ++ww) v += pj[(ww*8 + w)*48 + lane];
    }
    float mx = v;
    #pragma unroll
    for (int m = 1; m < 64; m <<= 1) mx = fmaxf(mx, __shfl_xor(mx, m));
    float e = (lane < NB) ? __expf(v - mx) : 0.f;
    float es = e;
    #pragma unroll
    for (int m = 1; m < 64; m <<= 1) es += __shfl_xor(es, m);
    const float wgt = e / es;   // lane's weight for field n=lane
    float accp = 0.f;
    #pragma unroll 8
    for (int n = 0; n < NB; ++n)
      accp += b2f16(hL[w*2568 + n*64 + lane]) * __shfl(wgt, n);
    out[((size_t)(b0 + w)*2 + t)*64 + lane] = accp;
  }
}

extern "C" void kernel_launch(void* const* d_in, const int* in_sizes, int n_in,
                              void* d_out, int out_size, void* d_ws, size_t ws_size,
                              hipStream_t stream) {
  const float* x        = (const float*)d_in[0];
  const float* masker   = (const float*)d_in[1];
  const float* ln_gamma = (const float*)d_in[2];
  const float* ln_beta  = (const float*)d_in[3];
  const float* gnn_w    = (const float*)d_in[4];
  const float* gnn_b    = (const float*)d_in[5];
  const float* bn_gamma = (const float*)d_in[6];
  const float* bn_beta  = (const float*)d_in[7];
  const float* bn_mean  = (const float*)d_in[8];
  const float* bn_var   = (const float*)d_in[9];
  const float* gate_w   = (const float*)d_in[10];
  const float* gate_b   = (const float*)d_in[11];
  float* out = (float*)d_out;

  char* ws = (char*)d_ws;
  unsigned short* A1pk   = (unsigned short*)(ws + 0);
  unsigned short* W2pk   = (unsigned short*)(ws + 12288);
  unsigned short* Gpk    = (unsigned short*)(ws + 45056);
  float*          s1     = (float*)(ws + 290816);
  float*          sNT    = (float*)(ws + 311296);
  float*          bias2T = (float*)(ws + 331904);

  prep<<<64, 256, 0, stream>>>(masker, ln_gamma, ln_beta, gnn_w, gnn_b,
                               bn_gamma, bn_beta, bn_mean, bn_var, gate_w,
                               A1pk, W2pk, Gpk, s1, sNT, bias2T);
  kernelM<<<2048, 512, 0, stream>>>(x, A1pk, W2pk, Gpk,
                                    s1, sNT, bias2T, gate_b, out);
}

// Round 12
// 234.363 us; speedup vs baseline: 1.0342x; 1.0342x over previous
//
#include <hip/hip_runtime.h>
#include <hip/hip_bf16.h>
#include <stdint.h>

typedef float v4f __attribute__((ext_vector_type(4)));
typedef short v8s __attribute__((ext_vector_type(8)));
typedef union { v8s v; unsigned u[4]; } v8u;

#define NB 40
#define XSTR 42     // xT row stride in shorts (21 dwords) — 4-way max bank aliasing

__device__ __forceinline__ unsigned short f2b(float f) {
  __hip_bfloat16 h = __float2bfloat16(f);
  unsigned short u;
  __builtin_memcpy(&u, &h, 2);
  return u;
}
__device__ __forceinline__ unsigned pk2(float lo, float hi) {
  __hip_bfloat162 h = __float22bfloat162_rn(make_float2(lo, hi));
  unsigned u;
  __builtin_memcpy(&u, &h, 4);
  return u;
}
__device__ __forceinline__ float b2f16(unsigned short h) {
  return __uint_as_float(((unsigned)h) << 16);
}
__device__ __forceinline__ float blo(unsigned u) { return __uint_as_float(u << 16); }
__device__ __forceinline__ float bhi(unsigned u) { return __uint_as_float(u & 0xFFFF0000u); }

// ws layout (bytes):
//  A1pk   @ 0        : 12288     (2t x 3nt x 2ks A^T A-frags, zero n>=40 / m>=40)
//  W2pk   @ 12288    : 32768     (2t x 4ks x 4dt B-frags of gnn_w)
//  Gpk    @ 45056    : 245760    (80kt x 3jt A-frags of gate_w^T, K n-major fl=n*64+d)
//  s1     @ 290816   : 20480     s for f<64, [t][n][d] f32
//  sNT    @ 311296   : 20480+128 s for f>=64, [t][d][n] f32 (+pad)
//  bias2T @ 331904   : 20480     gnn_b + all-BN-offset fold, [t][d][n] f32

// prep: params only. block 0: adjacency -> LN -> softmax -> A1pk (wave-parallel).
// blocks 1..63: everything else.
__global__ __launch_bounds__(256) void prep(
    const float* __restrict__ masker,
    const float* __restrict__ ln_gamma, const float* __restrict__ ln_beta,
    const float* __restrict__ gnn_w, const float* __restrict__ gnn_b,
    const float* __restrict__ bn_gamma, const float* __restrict__ bn_beta,
    const float* __restrict__ bn_mean, const float* __restrict__ bn_var,
    const float* __restrict__ gate_w,
    unsigned short* __restrict__ A1pk, unsigned short* __restrict__ W2pk,
    unsigned short* __restrict__ Gpk, float* __restrict__ s1,
    float* __restrict__ sNT, float* __restrict__ bias2T)
{
  const int tid = threadIdx.x;
  if (blockIdx.x == 0) {
    __shared__ float AtL[2 * NB * NB];
    const int w = tid >> 6, lane = tid & 63;
    #pragma unroll 1
    for (int it = 0; it < 20; ++it) {
      const int c = it * 4 + w;        // 0..79
      const int t = c / NB, n = c % NB;
      const int m = lane;              // valid < 40
      float adj = 0.f;
      if (m < NB) {
        float p = masker[((t*3+0)*NB+m)*NB+n]
                * masker[((t*3+1)*NB+m)*NB+n]
                * masker[((t*3+2)*NB+m)*NB+n];
        adj = p > 0.f ? p : 0.f;
      }
      float s = adj;
      #pragma unroll
      for (int d = 1; d < 64; d <<= 1) s += __shfl_xor(s, d);
      const float mu = s * (1.f/NB);
      const float dv = (m < NB) ? adj - mu : 0.f;
      float v2 = dv * dv;
      #pragma unroll
      for (int d = 1; d < 64; d <<= 1) v2 += __shfl_xor(v2, d);
      const float inv = rsqrtf(v2 * (1.f/NB) + 1e-5f);
      float val = -3.0e38f;
      if (m < NB) {
        float lnv = dv * inv * ln_gamma[m] + ln_beta[m];
        val = lnv + (adj != 0.f ? 0.f : -1e9f) + (m == n ? 1.f : 0.f);
      }
      float mx = val;
      #pragma unroll
      for (int d = 1; d < 64; d <<= 1) mx = fmaxf(mx, __shfl_xor(mx, d));
      const float e = (m < NB) ? __expf(val - mx) : 0.f;
      float es = e;
      #pragma unroll
      for (int d = 1; d < 64; d <<= 1) es += __shfl_xor(es, d);
      if (m < NB)
        AtL[(t*NB+n)*NB + m] = (adj != 0.f) ? e / es : 0.f;
    }
    __syncthreads();
    for (int e = tid; e < 6144; e += 256) {
      int frag = e >> 9, rem = e & 511, lane2 = rem >> 3, jj = rem & 7;
      int t = frag / 6, r2 = frag % 6, nt = r2 >> 1, ks = r2 & 1;
      int n = nt*16 + (lane2 & 15);
      int m = ks*32 + (lane2 >> 4)*8 + jj;
      A1pk[e] = f2b((n < NB && m < NB) ? AtL[(t*NB+n)*NB+m] : 0.f);
    }
  } else {
    const int gid = (blockIdx.x - 1) * 256 + tid, gsz = 63 * 256;
    for (int e = gid; e < 16384; e += gsz) {
      int frag = e >> 9, rem = e & 511, lane = rem >> 3, jj = rem & 7;
      int t = frag >> 4, ks = (frag >> 2) & 3, dt = frag & 3;
      int f = ks*32 + (lane >> 4)*8 + jj, d = dt*16 + (lane & 15);
      W2pk[e] = f2b(gnn_w[t*8192 + f*64 + d]);
    }
    // Gpk: K n-major (fl = n*64+d flat index), matches hL layout in kernelM
    for (int e = gid; e < 122880; e += gsz) {
      int frag = e >> 9, rem = e & 511, lane = rem >> 3, jj = rem & 7;
      int kt = frag / 3, jt = frag % 3;
      int fl = kt*32 + (lane >> 4)*8 + jj, j = jt*16 + (lane & 15);
      Gpk[e] = f2b(j < NB ? gate_w[fl*NB + j] : 0.f);
    }
    for (int e = gid; e < 5120; e += gsz) {
      int t = e / 2560, n = (e % 2560) / 64, d = e & 63;
      int F = (t*NB + n)*128 + d;
      s1[e] = bn_gamma[F] * rsqrtf(bn_var[F] + 1e-5f);
    }
    for (int e = gid; e < 5120; e += gsz) {
      int t = e / 2560, d = (e % 2560) / 40, n = e % 40;
      int F = (t*NB + n)*128 + 64 + d;
      sNT[e] = bn_gamma[F] * rsqrtf(bn_var[F] + 1e-5f);
    }
    for (int e4 = gid; e4 < 20480; e4 += gsz) {
      int e = e4 >> 2, part = e4 & 3;
      int t = e / 2560, d = (e % 2560) / 40, n = e % 40;
      float acc = (part == 0) ? gnn_b[(t*NB + n)*64 + d] : 0.f;
      int Fb = (t*NB + n)*128;
      int f0 = part * 32;
      for (int f = f0; f < f0 + 32; ++f) {
        float s = bn_gamma[Fb+f] * rsqrtf(bn_var[Fb+f] + 1e-5f);
        float o = bn_beta[Fb+f] - bn_mean[Fb+f] * s;
        acc += o * gnn_w[t*8192 + f*64 + d];
      }
      acc += __shfl_xor(acc, 1);
      acc += __shfl_xor(acc, 2);
      if (part == 0) bias2T[e] = acc;
    }
  }
}

// kernelM: r10 structure verbatim (t-split, 4 batches/block, U in LDS, 46.6 KB,
// XSTR=42 xT staging) + XCD t-pair swizzle: blocks bid and bid+8 share the same
// batch group (t=0/1) and land on the same XCD under round-robin dispatch, so
// the t=1 block's x reads hit that XCD's L2 (r11 measured FETCH 83->42 MB).
__global__ __launch_bounds__(256) void kernelM(
    const float* __restrict__ x,
    const unsigned short* __restrict__ A1pk, const unsigned short* __restrict__ W2pk,
    const unsigned short* __restrict__ Gpk, const float* __restrict__ s1,
    const float* __restrict__ sNT, const float* __restrict__ bias2T,
    const float* __restrict__ gate_b, float* __restrict__ out)
{
  __shared__ __align__(16) unsigned short hc[160 * 136];  // 43520 B (xT / U|V / hL)
  __shared__ float pj[16 * 48];                           // 3072 B

  const int tid = threadIdx.x;
  const int lane = tid & 63;
  const int w = tid >> 6;
  const int l = lane & 15, q = lane >> 4;
  const int bid = blockIdx.x;
  const int t  = (bid >> 3) & 1;
  const int bg = (bid & 7) | ((bid >> 4) << 3);   // 0..2047; t-pair -> same XCD
  const int b0 = bg * 4;
  unsigned* hcU = (unsigned*)hc;
  unsigned short* hL = hc;   // alias: hL (4*2568 sh) lives in hc after GEMM2

  // ---- load x f32 -> packed bf16 regs ----
  uint4 xr[5];
  #pragma unroll
  for (int it = 0; it < 5; ++it) {
    const int c = it * 256 + tid, row = c >> 3, dp8 = c & 7;
    const float* xp = x + (size_t)b0 * 2560 + row * 64 + dp8 * 8;
    const float4 f0 = *(const float4*)xp;
    const float4 f1 = *(const float4*)(xp + 4);
    xr[it] = make_uint4(pk2(f0.x, f0.y), pk2(f0.z, f0.w),
                        pk2(f1.x, f1.y), pk2(f1.z, f1.w));
  }
  // ---- zero xT pads: cols 40,41 of each of 256 rows + 12-dword tail ----
  for (int k = tid; k < 268; k += 256)
    hcU[(k < 256) ? (k * 21 + 20) : (5376 + (k - 256))] = 0u;
  // ---- xT stage: rows R=(bq*64+d), XSTR=42-short stride, scalar u16 scatter ----
  #pragma unroll
  for (int it = 0; it < 5; ++it) {
    const int c = it * 256 + tid, row = c >> 3, dp8 = c & 7;
    const int bq = row / NB, n = row - bq * NB;
    unsigned short* base = hc + (bq * 64 + dp8 * 8) * XSTR + n;
    const unsigned uu0 = xr[it].x, uu1 = xr[it].y, uu2 = xr[it].z, uu3 = xr[it].w;
    base[0*XSTR] = (unsigned short)(uu0 & 0xFFFF);
    base[1*XSTR] = (unsigned short)(uu0 >> 16);
    base[2*XSTR] = (unsigned short)(uu1 & 0xFFFF);
    base[3*XSTR] = (unsigned short)(uu1 >> 16);
    base[4*XSTR] = (unsigned short)(uu2 & 0xFFFF);
    base[5*XSTR] = (unsigned short)(uu2 >> 16);
    base[6*XSTR] = (unsigned short)(uu3 & 0xFFFF);
    base[7*XSTR] = (unsigned short)(uu3 >> 16);
  }
  __syncthreads();
  // ---- b1 frags: 4 dword loads each (reads past col 42 hit next row's finite
  // data or the zeroed tail; those k-slots multiply A1pk zeros) ----
  v8s b1[4][2];
  #pragma unroll
  for (int i = 0; i < 4; ++i) {
    const int R = (w * 4 + i) * 16 + l;   // 0..255
    #pragma unroll
    for (int ks = 0; ks < 2; ++ks) {
      const unsigned* p = hcU + R * 21 + ks * 16 + q * 4;
      v8u uu;
      uu.u[0] = p[0]; uu.u[1] = p[1]; uu.u[2] = p[2]; uu.u[3] = p[3];
      b1[i][ks] = uu.v;
    }
  }
  __syncthreads();

  // per-t fragments
  v8s a1[3][2], w2[4];
  #pragma unroll
  for (int nt = 0; nt < 3; ++nt)
    #pragma unroll
    for (int ks = 0; ks < 2; ++ks)
      a1[nt][ks] = *(const v8s*)(A1pk + (((t*3 + nt)*2 + ks) << 9) + lane*8);
  #pragma unroll
  for (int ks = 0; ks < 4; ++ks)
    w2[ks] = *(const v8s*)(W2pk + (((t*4 + ks)*4 + w) << 9) + lane*8);

  // ---- Phase A: hc x-half = s1 .* x ----
  #pragma unroll
  for (int it = 0; it < 5; ++it) {
    const int c = it*256 + tid;
    const int row = c >> 3, dp8 = c & 7;
    const uint4 xv = xr[it];
    const int n = row % NB;
    const float4 sA = *(const float4*)(s1 + (t*NB + n)*64 + dp8*8);
    const float4 sB = *(const float4*)(s1 + (t*NB + n)*64 + dp8*8 + 4);
    uint4 p;
    p.x = pk2(blo(xv.x)*sA.x, bhi(xv.x)*sA.y);
    p.y = pk2(blo(xv.y)*sA.z, bhi(xv.y)*sA.w);
    p.z = pk2(blo(xv.z)*sB.x, bhi(xv.z)*sB.y);
    p.w = pk2(blo(xv.w)*sB.z, bhi(xv.w)*sB.w);
    *(uint4*)(hcU + row*68 + dp8*4) = p;
  }
  // ---- GEMM1 + scale -> hc nei-half ----
  #pragma unroll
  for (int i = 0; i < 4; ++i) {
    const int R = (w*4+i)*16 + l;
    const int bb = R >> 6, d = R & 63;
    #pragma unroll
    for (int nt = 0; nt < 3; ++nt) {
      v4f acc = {0.f, 0.f, 0.f, 0.f};
      acc = __builtin_amdgcn_mfma_f32_16x16x32_bf16(a1[nt][0], b1[i][0], acc, 0, 0, 0);
      acc = __builtin_amdgcn_mfma_f32_16x16x32_bf16(a1[nt][1], b1[i][1], acc, 0, 0, 0);
      const float4 sv = *(const float4*)(sNT + (t*64+d)*40 + nt*16 + q*4);
      #pragma unroll
      for (int r = 0; r < 4; ++r) {
        int n = nt*16 + q*4 + r;
        if (n < NB) hc[(bb*NB + n)*136 + 64 + d] = f2b(acc[r]*sv[r]);
      }
    }
  }
  __syncthreads();
  // ---- GEMM2 + bias2T -> packed regs (hL aliases hc, write after barrier) ----
  unsigned pkr0[10], pkr1[10];
  #pragma unroll
  for (int mt = 0; mt < 10; ++mt) {
    v4f acc = {0.f, 0.f, 0.f, 0.f};
    #pragma unroll
    for (int ks = 0; ks < 4; ++ks) {
      v8s af = *(const v8s*)(hc + (mt*16 + l)*136 + ks*32 + q*8);
      acc = __builtin_amdgcn_mfma_f32_16x16x32_bf16(af, w2[ks], acc, 0, 0, 0);
    }
    const int d = w*16 + l;
    const int G = mt*16 + q*4;
    const int bb = G / NB, n0 = G - bb*NB;
    const float4 bv = *(const float4*)(bias2T + (t*64+d)*40 + n0);
    pkr0[mt] = pk2(acc[0] + bv.x, acc[1] + bv.y);
    pkr1[mt] = pk2(acc[2] + bv.z, acc[3] + bv.w);
  }
  __syncthreads();
  #pragma unroll
  for (int mt = 0; mt < 10; ++mt) {
    const int d = w*16 + l;
    const int G = mt*16 + q*4;
    const int bb = G / NB, n0 = G - bb*NB;
    hL[bb*2568 + (n0+0)*64 + d] = (unsigned short)(pkr0[mt] & 0xFFFF);
    hL[bb*2568 + (n0+1)*64 + d] = (unsigned short)(pkr0[mt] >> 16);
    hL[bb*2568 + (n0+2)*64 + d] = (unsigned short)(pkr1[mt] & 0xFFFF);
    hL[bb*2568 + (n0+3)*64 + d] = (unsigned short)(pkr1[mt] >> 16);
  }
  __syncthreads();
  // ---- GEMM3: logits (A=Gpk rows j, B=hL cols b); depth-2 Gpk prefetch ----
  v4f ac0 = {0,0,0,0}, ac1 = {0,0,0,0}, ac2 = {0,0,0,0};
  {
    v8s pg0[2], pg1[2], pg2[2], pbf[2];
    #pragma unroll
    for (int s = 0; s < 2; ++s) {
      const int kt = w + s*4;
      pg0[s] = *(const v8s*)(Gpk + ((kt*3+0) << 9) + lane*8);
      pg1[s] = *(const v8s*)(Gpk + ((kt*3+1) << 9) + lane*8);
      pg2[s] = *(const v8s*)(Gpk + ((kt*3+2) << 9) + lane*8);
      pbf[s] = *(const v8s*)(hL + (l & 3)*2568 + kt*32 + q*8);
    }
    #pragma unroll
    for (int i = 0; i < 20; ++i) {
      const int cur = i & 1;
      const v8s G0 = pg0[cur], G1 = pg1[cur], G2 = pg2[cur], BF = pbf[cur];
      if (i < 18) {
        const int ktn = w + (i+2)*4;
        pg0[cur] = *(const v8s*)(Gpk + ((ktn*3+0) << 9) + lane*8);
        pg1[cur] = *(const v8s*)(Gpk + ((ktn*3+1) << 9) + lane*8);
        pg2[cur] = *(const v8s*)(Gpk + ((ktn*3+2) << 9) + lane*8);
        pbf[cur] = *(const v8s*)(hL + (l & 3)*2568 + ktn*32 + q*8);
      }
      ac0 = __builtin_amdgcn_mfma_f32_16x16x32_bf16(G0, BF, ac0, 0, 0, 0);
      ac1 = __builtin_amdgcn_mfma_f32_16x16x32_bf16(G1, BF, ac1, 0, 0, 0);
      ac2 = __builtin_amdgcn_mfma_f32_16x16x32_bf16(G2, BF, ac2, 0, 0, 0);
    }
  }
  if (l < 4) {
    #pragma unroll
    for (int r = 0; r < 4; ++r) {
      pj[(w*4 + l)*48 +  0 + q*4 + r] = ac0[r];
      pj[(w*4 + l)*48 + 16 + q*4 + r] = ac1[r];
      pj[(w*4 + l)*48 + 32 + q*4 + r] = ac2[r];
    }
  }
  __syncthreads();
  // ---- per-wave softmax (batch = w) + pool ----
  {
    float v = -3.0e38f;
    if (lane < NB) {
      v = gate_b[lane];
      #pragma unroll
      for (int ww = 0; ww < 4; ++ww) v += pj[(ww*4 + w)*48 + lane];
    }
    float mx = v;
    #pragma unroll
    for (int m = 1; m < 64; m <<= 1) mx = fmaxf(mx, __shfl_xor(mx, m));
    float e = (lane < NB) ? __expf(v - mx) : 0.f;
    float es = e;
    #pragma unroll
    for (int m = 1; m < 64; m <<= 1) es += __shfl_xor(es, m);
    const float wgt = e / es;   // lane's weight for field n=lane
    float accp = 0.f;
    #pragma unroll 8
    for (int n = 0; n < NB; ++n)
      accp += b2f16(hL[w*2568 + n*64 + lane]) * __shfl(wgt, n);
    out[((size_t)(b0 + w)*2 + t)*64 + lane] = accp;
  }
}

extern "C" void kernel_launch(void* const* d_in, const int* in_sizes, int n_in,
                              void* d_out, int out_size, void* d_ws, size_t ws_size,
                              hipStream_t stream) {
  const float* x        = (const float*)d_in[0];
  const float* masker   = (const float*)d_in[1];
  const float* ln_gamma = (const float*)d_in[2];
  const float* ln_beta  = (const float*)d_in[3];
  const float* gnn_w    = (const float*)d_in[4];
  const float* gnn_b    = (const float*)d_in[5];
  const float* bn_gamma = (const float*)d_in[6];
  const float* bn_beta  = (const float*)d_in[7];
  const float* bn_mean  = (const float*)d_in[8];
  const float* bn_var   = (const float*)d_in[9];
  const float* gate_w   = (const float*)d_in[10];
  const float* gate_b   = (const float*)d_in[11];
  float* out = (float*)d_out;

  char* ws = (char*)d_ws;
  unsigned short* A1pk   = (unsigned short*)(ws + 0);
  unsigned short* W2pk   = (unsigned short*)(ws + 12288);
  unsigned short* Gpk    = (unsigned short*)(ws + 45056);
  float*          s1     = (float*)(ws + 290816);
  float*          sNT    = (float*)(ws + 311296);
  float*          bias2T = (float*)(ws + 331904);

  prep<<<64, 256, 0, stream>>>(masker, ln_gamma, ln_beta, gnn_w, gnn_b,
                               bn_gamma, bn_beta, bn_mean, bn_var, gate_w,
                               A1pk, W2pk, Gpk, s1, sNT, bias2T);
  kernelM<<<4096, 256, 0, stream>>>(x, A1pk, W2pk, Gpk,
                                    s1, sNT, bias2T, gate_b, out);
}